// Round 13
// baseline (216.496 us; speedup 1.0000x reference)
//
#include <hip/hip_runtime.h>
#include <hip/hip_bf16.h>

#define NB   512   // sequence length N
#define DB   512   // model dim D
#define EB   64    // d_dir
#define JT   16    // j-rows per tile
#define TPB  16    // tiles per block (block covers 256 rows = half a bi)
#define PR   8     // bn-rows per proj block
#define WSTR 65    // LDS stride for transposed W chunks (conflict-free)

typedef __bf16 bf16x8 __attribute__((ext_vector_type(8)));
typedef float  f32x4  __attribute__((ext_vector_type(4)));

// ---- Kernel A: q = t@Wq^T, k = t@Wk^T (bf16) + fused Wv->bf16. (R12, unchanged) ----
__global__ __launch_bounds__(256) void qk_proj_bf16(
    const float* __restrict__ t,    // (B*N, 512)
    const float* __restrict__ Wq,   // (64, 512)
    const float* __restrict__ Wk,   // (64, 512)
    const float* __restrict__ Wv,   // (512, 64)
    __bf16* __restrict__ qb,        // (B*N, 64)
    __bf16* __restrict__ kb,        // (B*N, 64)
    __bf16* __restrict__ wvb)       // (512, 64)
{
    const int blk = blockIdx.x;     // 0..127
    const int bn0 = blk * PR;
    const int tid = threadIdx.x;
    const int e   = tid & 63;       // lane -> output e
    const int w   = tid >> 6;       // wave 0..3 -> rows 2w, 2w+1

    __shared__ float wqt[64 * WSTR];   // [d'][e], stride 65
    __shared__ float wkt[64 * WSTR];

    {
        const int r = blk * 4 + w;
        wvb[r * EB + e] = (__bf16)Wv[r * EB + e];
    }

    float aq0 = 0.f, ak0 = 0.f, aq1 = 0.f, ak1 = 0.f;
    const float* __restrict__ t0 = t + (size_t)(bn0 + 2 * w) * DB;  // uniform -> s_load
    const float* __restrict__ t1 = t0 + DB;

    const int er = tid >> 4;           // 0..15 (loader row group)
    const int dd = (tid & 15) * 4;     // 0..60 (loader d offset)

    for (int c = 0; c < 8; ++c) {
        const int d0 = c * 64;
        __syncthreads();

        #pragma unroll
        for (int g = 0; g < 4; ++g) {
            const int erow = er + g * 16;
            const f32x4 vq = *reinterpret_cast<const f32x4*>(Wq + (size_t)erow * DB + d0 + dd);
            const f32x4 vk = *reinterpret_cast<const f32x4*>(Wk + (size_t)erow * DB + d0 + dd);
            #pragma unroll
            for (int i = 0; i < 4; ++i) {
                wqt[(dd + i) * WSTR + erow] = vq[i];
                wkt[(dd + i) * WSTR + erow] = vk[i];
            }
        }
        __syncthreads();

        #pragma unroll 8
        for (int dp = 0; dp < 64; ++dp) {
            const float tq  = wqt[dp * WSTR + e];
            const float tk  = wkt[dp * WSTR + e];
            const float tv0 = t0[d0 + dp];
            const float tv1 = t1[d0 + dp];
            aq0 += tv0 * tq;  ak0 += tv0 * tk;
            aq1 += tv1 * tq;  ak1 += tv1 * tk;
        }
    }

    const size_t r0 = (size_t)(bn0 + 2 * w) * EB + e;
    qb[r0]      = (__bf16)aq0;
    kb[r0]      = (__bf16)ak0;
    qb[r0 + EB] = (__bf16)aq1;
    kb[r0 + EB] = (__bf16)ak1;
}

// ---- Kernel B (persistent, barrier-free, FOUR-deep store register staging) ----
// out[b,i,j,d] = sum_e k[b,j,e] * (q[b,i,e] * Wv[d,e])
// R12 base, ONE change: store-data registers are a persistent stage[4][8]
// (slot = t&3, loop fully unrolled -> all indices static). A slot's registers
// are only overwritten 4 tiles (~10us) after its stores issue, so vmcnt never
// drains a store on the critical path unless ack latency > 10us.
// (k prefetch reverted to simple 1-ahead to pay the VGPR bill; R11 showed
// the depth-8 window was perf-neutral.)
__global__ __launch_bounds__(256) void kappa_mfma(
    const __bf16* __restrict__ qb,   // (B*N, 64)
    const __bf16* __restrict__ kb,   // (B*N, 64)
    const __bf16* __restrict__ wvb,  // (512, 64)  [d][e]
    float* __restrict__ out)         // (B*N, N, 512)
{
    const int blk = blockIdx.x;          // 0..2047
    const int bi  = blk >> 1;            // 0..1023  (= b*N + i)
    const int b   = bi >> 9;             // batch
    const int jt0 = (blk & 1) * TPB;     // tile base within the bi
    const int w    = threadIdx.x >> 6;   // wave 0..3 -> d-quarter
    const int l    = threadIdx.x & 63;
    const int lrow = l & 15;
    const int lgrp = l >> 4;             // e-chunk base = lgrp*8
    const int dbase = w * 128;

    __shared__ float lds[2 * 4 * JT * 128];   // 64 KB: [parity][wave][16][128]
    float* __restrict__ wtA = lds + w * (JT * 128);
    float* __restrict__ wtB = lds + 4 * JT * 128 + w * (JT * 128);

    // q chunks (loop-invariant)
    const bf16x8 qv0 = *reinterpret_cast<const bf16x8*>(qb + (size_t)bi * EB + lgrp * 8);
    const bf16x8 qv1 = *reinterpret_cast<const bf16x8*>(qb + (size_t)bi * EB + 32 + lgrp * 8);

    // Wv fragments with q folded in (once per block). m=d, lane lrow = d%16.
    bf16x8 bfrag[8][2];
    #pragma unroll
    for (int df = 0; df < 8; ++df) {
        const int d = dbase + df * 16 + lrow;
        #pragma unroll
        for (int ks = 0; ks < 2; ++ks) {
            const bf16x8 wv = *reinterpret_cast<const bf16x8*>(
                wvb + (size_t)d * EB + ks * 32 + lgrp * 8);
            const bf16x8 qq = ks ? qv1 : qv0;
            bf16x8 f;
            #pragma unroll
            for (int x = 0; x < 8; ++x)
                f[x] = (__bf16)((float)wv[x] * (float)qq[x]);
            bfrag[df][ks] = f;
        }
    }

    const __bf16* __restrict__ kbase = kb + (size_t)b * NB * EB;

    // prefetch k rows for tile 0
    bf16x8 kv0 = *reinterpret_cast<const bf16x8*>(kbase + (size_t)(jt0 * JT + lrow) * EB + lgrp * 8);
    bf16x8 kv1 = *reinterpret_cast<const bf16x8*>(kbase + (size_t)(jt0 * JT + lrow) * EB + 32 + lgrp * 8);

    const int r_lo = l >> 5;        // 0/1: epilogue row parity
    const int cc   = l & 31;        // epilogue d-chunk (16B units)

    // persistent 4-deep store staging (all indices static under full unroll)
    f32x4 stage[4][8];

    #pragma unroll
    for (int t = 0; t < TPB; ++t) {
        const int slot = t & 3;

        // MFMA: acc[df][r] = out[j=jb+lrow][d=dbase+df*16+lgrp*4+r]
        f32x4 acc[8];
        #pragma unroll
        for (int df = 0; df < 8; ++df) {
            acc[df] = (f32x4){0.f, 0.f, 0.f, 0.f};
            acc[df] = __builtin_amdgcn_mfma_f32_16x16x32_bf16(bfrag[df][0], kv0, acc[df], 0, 0, 0);
            acc[df] = __builtin_amdgcn_mfma_f32_16x16x32_bf16(bfrag[df][1], kv1, acc[df], 0, 0, 0);
        }

        // prefetch k for next tile
        if (t + 1 < TPB) {
            const int jn = (jt0 + t + 1) * JT + lrow;
            kv0 = *reinterpret_cast<const bf16x8*>(kbase + (size_t)jn * EB + lgrp * 8);
            kv1 = *reinterpret_cast<const bf16x8*>(kbase + (size_t)jn * EB + 32 + lgrp * 8);
        }

        float* __restrict__ wtile = (t & 1) ? wtB : wtA;

        // acc -> wave-private LDS, XOR-16B swizzle (conflict-free both sides)
        asm volatile("" ::: "memory");
        #pragma unroll
        for (int df = 0; df < 8; ++df) {
            const int sc = (df * 4 + lgrp) ^ (lrow & 7);
            *reinterpret_cast<f32x4*>(wtile + lrow * 128 + sc * 4) = acc[df];
        }
        asm volatile("" ::: "memory");

        // read back linear into slot's registers (overwrites regs whose
        // stores issued 4 tiles ago), then store 2 rows x 512B per pass
        #pragma unroll
        for (int p = 0; p < 8; ++p) {
            const int r  = 2 * p + r_lo;
            const int sc = cc ^ (r & 7);
            stage[slot][p] = *reinterpret_cast<const f32x4*>(wtile + r * 128 + sc * 4);
        }
        float* __restrict__ obase =
            out + ((size_t)bi * NB + (size_t)(jt0 + t) * JT) * DB + dbase;
        #pragma unroll
        for (int p = 0; p < 8; ++p) {
            const int r = 2 * p + r_lo;
            *reinterpret_cast<f32x4*>(obase + (size_t)r * DB + cc * 4) = stage[slot][p];
        }
    }
}

extern "C" void kernel_launch(void* const* d_in, const int* in_sizes, int n_in,
                              void* d_out, int out_size, void* d_ws, size_t ws_size,
                              hipStream_t stream) {
    const float* t  = (const float*)d_in[0];  // (2,512,512)
    const float* Wq = (const float*)d_in[1];  // (64,512)
    const float* Wk = (const float*)d_in[2];  // (64,512)
    const float* Wv = (const float*)d_in[3];  // (512,64)
    float* out = (float*)d_out;

    const int B = 2;

    __bf16* qb  = (__bf16*)d_ws;                       // B*N*64
    __bf16* kbf = qb + (size_t)B * NB * EB;            // B*N*64
    __bf16* wvb = kbf + (size_t)B * NB * EB;           // 512*64

    qk_proj_bf16<<<dim3(128), dim3(256), 0, stream>>>(t, Wq, Wk, Wv, qb, kbf, wvb);

    kappa_mfma<<<dim3(2048), dim3(256), 0, stream>>>(qb, kbf, wvb, out);
}

// Round 14
// 214.025 us; speedup vs baseline: 1.0115x; 1.0115x over previous
//
#include <hip/hip_runtime.h>
#include <hip/hip_bf16.h>

#define NB   512   // sequence length N
#define DB   512   // model dim D
#define EB   64    // d_dir
#define JT   16    // j-rows per tile
#define TPB  16    // tiles per block (block covers 256 rows = half a bi)
#define PR   8     // bn-rows per proj block
#define WSTR 65    // LDS stride for transposed W chunks (conflict-free)

typedef __bf16 bf16x8 __attribute__((ext_vector_type(8)));
typedef float  f32x4  __attribute__((ext_vector_type(4)));

// ---- Kernel A: q = t@Wq^T, k = t@Wk^T (bf16) + fused Wv->bf16. (R12, unchanged) ----
__global__ __launch_bounds__(256) void qk_proj_bf16(
    const float* __restrict__ t,    // (B*N, 512)
    const float* __restrict__ Wq,   // (64, 512)
    const float* __restrict__ Wk,   // (64, 512)
    const float* __restrict__ Wv,   // (512, 64)
    __bf16* __restrict__ qb,        // (B*N, 64)
    __bf16* __restrict__ kb,        // (B*N, 64)
    __bf16* __restrict__ wvb)       // (512, 64)
{
    const int blk = blockIdx.x;     // 0..127
    const int bn0 = blk * PR;
    const int tid = threadIdx.x;
    const int e   = tid & 63;       // lane -> output e
    const int w   = tid >> 6;       // wave 0..3 -> rows 2w, 2w+1

    __shared__ float wqt[64 * WSTR];   // [d'][e], stride 65
    __shared__ float wkt[64 * WSTR];

    {
        const int r = blk * 4 + w;
        wvb[r * EB + e] = (__bf16)Wv[r * EB + e];
    }

    float aq0 = 0.f, ak0 = 0.f, aq1 = 0.f, ak1 = 0.f;
    const float* __restrict__ t0 = t + (size_t)(bn0 + 2 * w) * DB;  // uniform -> s_load
    const float* __restrict__ t1 = t0 + DB;

    const int er = tid >> 4;           // 0..15 (loader row group)
    const int dd = (tid & 15) * 4;     // 0..60 (loader d offset)

    for (int c = 0; c < 8; ++c) {
        const int d0 = c * 64;
        __syncthreads();

        #pragma unroll
        for (int g = 0; g < 4; ++g) {
            const int erow = er + g * 16;
            const f32x4 vq = *reinterpret_cast<const f32x4*>(Wq + (size_t)erow * DB + d0 + dd);
            const f32x4 vk = *reinterpret_cast<const f32x4*>(Wk + (size_t)erow * DB + d0 + dd);
            #pragma unroll
            for (int i = 0; i < 4; ++i) {
                wqt[(dd + i) * WSTR + erow] = vq[i];
                wkt[(dd + i) * WSTR + erow] = vk[i];
            }
        }
        __syncthreads();

        #pragma unroll 8
        for (int dp = 0; dp < 64; ++dp) {
            const float tq  = wqt[dp * WSTR + e];
            const float tk  = wkt[dp * WSTR + e];
            const float tv0 = t0[d0 + dp];
            const float tv1 = t1[d0 + dp];
            aq0 += tv0 * tq;  ak0 += tv0 * tk;
            aq1 += tv1 * tq;  ak1 += tv1 * tk;
        }
    }

    const size_t r0 = (size_t)(bn0 + 2 * w) * EB + e;
    qb[r0]      = (__bf16)aq0;
    kb[r0]      = (__bf16)ak0;
    qb[r0 + EB] = (__bf16)aq1;
    kb[r0 + EB] = (__bf16)ak1;
}

// ---- Kernel B: 512-thread blocks, 8 waves x 64-d slices, block-shared
// double-buffered LDS tile [16][512] (64KB) -> 2 blocks/CU but 16 waves/CU
// (2x the wave concurrency of R13). Epilogue stores ONE contiguous 1KB
// segment per wave instruction (terminal point of the segment-width axis:
// 64B->285us, 256B->249, 512B->220). One __syncthreads per tile; R10's
// 2-deep store-reg pipeline kept via parity-named register sets (ve/vo).
// out[b,i,j,d] = sum_e k[b,j,e] * (q[b,i,e] * Wv[d,e])
__global__ __launch_bounds__(512) void kappa_mfma(
    const __bf16* __restrict__ qb,   // (B*N, 64)
    const __bf16* __restrict__ kb,   // (B*N, 64)
    const __bf16* __restrict__ wvb,  // (512, 64)  [d][e]
    float* __restrict__ out)         // (B*N, N, 512)
{
    const int blk = blockIdx.x;          // 0..2047
    const int bi  = blk >> 1;            // 0..1023  (= b*N + i)
    const int b   = bi >> 9;             // batch
    const int jt0 = (blk & 1) * TPB;     // tile base within the bi
    const int tid = threadIdx.x;
    const int w    = tid >> 6;           // wave 0..7 -> 64-wide d-slice
    const int l    = tid & 63;
    const int lrow = l & 15;
    const int lgrp = l >> 4;             // e-chunk base = lgrp*8
    const int dbase = w * 64;

    __shared__ float lds[2 * JT * DB];   // 64 KB: two [16][512] tiles
    float* __restrict__ bufA = lds;
    float* __restrict__ bufB = lds + JT * DB;

    // q chunks (loop-invariant)
    const bf16x8 qv0 = *reinterpret_cast<const bf16x8*>(qb + (size_t)bi * EB + lgrp * 8);
    const bf16x8 qv1 = *reinterpret_cast<const bf16x8*>(qb + (size_t)bi * EB + 32 + lgrp * 8);

    // Wv fragments with q folded in (once per block). m=d, lane lrow = d%16.
    bf16x8 bfrag[4][2];
    #pragma unroll
    for (int df = 0; df < 4; ++df) {
        const int d = dbase + df * 16 + lrow;
        #pragma unroll
        for (int ks = 0; ks < 2; ++ks) {
            const bf16x8 wv = *reinterpret_cast<const bf16x8*>(
                wvb + (size_t)d * EB + ks * 32 + lgrp * 8);
            const bf16x8 qq = ks ? qv1 : qv0;
            bf16x8 f;
            #pragma unroll
            for (int x = 0; x < 8; ++x)
                f[x] = (__bf16)((float)wv[x] * (float)qq[x]);
            bfrag[df][ks] = f;
        }
    }

    const __bf16* __restrict__ kbase = kb + (size_t)b * NB * EB;

    // prefetch k rows for tile 0
    bf16x8 kv0 = *reinterpret_cast<const bf16x8*>(kbase + (size_t)(jt0 * JT + lrow) * EB + lgrp * 8);
    bf16x8 kv1 = *reinterpret_cast<const bf16x8*>(kbase + (size_t)(jt0 * JT + lrow) * EB + 32 + lgrp * 8);

    // epilogue indexing: row-within-pass er = tid>>7 (uniform per wave),
    // 16B-chunk-in-row ec = tid&127 -> wave covers 1KB contiguous.
    const int er = tid >> 7;        // 0..3
    const int ec = tid & 127;       // 0..127

    #pragma unroll
    for (int t2 = 0; t2 < TPB; t2 += 2) {
        // ================= EVEN tile (t2) — buffer A, regs ve =================
        {
            f32x4 acc[4];
            #pragma unroll
            for (int df = 0; df < 4; ++df) {
                acc[df] = (f32x4){0.f, 0.f, 0.f, 0.f};
                acc[df] = __builtin_amdgcn_mfma_f32_16x16x32_bf16(bfrag[df][0], kv0, acc[df], 0, 0, 0);
                acc[df] = __builtin_amdgcn_mfma_f32_16x16x32_bf16(bfrag[df][1], kv1, acc[df], 0, 0, 0);
            }
            {   // prefetch k for t2+1
                const int jn = (jt0 + t2 + 1) * JT + lrow;
                kv0 = *reinterpret_cast<const bf16x8*>(kbase + (size_t)jn * EB + lgrp * 8);
                kv1 = *reinterpret_cast<const bf16x8*>(kbase + (size_t)jn * EB + 32 + lgrp * 8);
            }
            // acc -> LDS: logical chunk w*16+df*4+lgrp in row lrow, XOR-swizzled
            #pragma unroll
            for (int df = 0; df < 4; ++df) {
                const int sc = w * 16 + ((df * 4 + lgrp) ^ (lrow & 7));
                *reinterpret_cast<f32x4*>(bufA + lrow * DB + sc * 4) = acc[df];
            }
            __syncthreads();
            // read 4 passes (unswizzle), then 4x 1KB-segment stores
            f32x4 ve[4];
            #pragma unroll
            for (int p = 0; p < 4; ++p) {
                const int r  = p * 4 + er;
                const int sc = (ec & ~15) | ((ec & 15) ^ (r & 7));
                ve[p] = *reinterpret_cast<const f32x4*>(bufA + r * DB + sc * 4);
            }
            float* __restrict__ obase =
                out + ((size_t)bi * NB + (size_t)(jt0 + t2) * JT) * DB;
            #pragma unroll
            for (int p = 0; p < 4; ++p) {
                const int r = p * 4 + er;
                *reinterpret_cast<f32x4*>(obase + (size_t)r * DB + ec * 4) = ve[p];
            }
        }
        // ================= ODD tile (t2+1) — buffer B, regs vo =================
        {
            f32x4 acc[4];
            #pragma unroll
            for (int df = 0; df < 4; ++df) {
                acc[df] = (f32x4){0.f, 0.f, 0.f, 0.f};
                acc[df] = __builtin_amdgcn_mfma_f32_16x16x32_bf16(bfrag[df][0], kv0, acc[df], 0, 0, 0);
                acc[df] = __builtin_amdgcn_mfma_f32_16x16x32_bf16(bfrag[df][1], kv1, acc[df], 0, 0, 0);
            }
            if (t2 + 2 < TPB) {
                const int jn = (jt0 + t2 + 2) * JT + lrow;
                kv0 = *reinterpret_cast<const bf16x8*>(kbase + (size_t)jn * EB + lgrp * 8);
                kv1 = *reinterpret_cast<const bf16x8*>(kbase + (size_t)jn * EB + 32 + lgrp * 8);
            }
            #pragma unroll
            for (int df = 0; df < 4; ++df) {
                const int sc = w * 16 + ((df * 4 + lgrp) ^ (lrow & 7));
                *reinterpret_cast<f32x4*>(bufB + lrow * DB + sc * 4) = acc[df];
            }
            __syncthreads();
            f32x4 vo[4];
            #pragma unroll
            for (int p = 0; p < 4; ++p) {
                const int r  = p * 4 + er;
                const int sc = (ec & ~15) | ((ec & 15) ^ (r & 7));
                vo[p] = *reinterpret_cast<const f32x4*>(bufB + r * DB + sc * 4);
            }
            float* __restrict__ obase =
                out + ((size_t)bi * NB + (size_t)(jt0 + t2 + 1) * JT) * DB;
            #pragma unroll
            for (int p = 0; p < 4; ++p) {
                const int r = p * 4 + er;
                *reinterpret_cast<f32x4*>(obase + (size_t)r * DB + ec * 4) = vo[p];
            }
        }
    }
}

extern "C" void kernel_launch(void* const* d_in, const int* in_sizes, int n_in,
                              void* d_out, int out_size, void* d_ws, size_t ws_size,
                              hipStream_t stream) {
    const float* t  = (const float*)d_in[0];  // (2,512,512)
    const float* Wq = (const float*)d_in[1];  // (64,512)
    const float* Wk = (const float*)d_in[2];  // (64,512)
    const float* Wv = (const float*)d_in[3];  // (512,64)
    float* out = (float*)d_out;

    const int B = 2;

    __bf16* qb  = (__bf16*)d_ws;                       // B*N*64
    __bf16* kbf = qb + (size_t)B * NB * EB;            // B*N*64
    __bf16* wvb = kbf + (size_t)B * NB * EB;           // 512*64

    qk_proj_bf16<<<dim3(128), dim3(256), 0, stream>>>(t, Wq, Wk, Wv, qb, kbf, wvb);

    kappa_mfma<<<dim3(2048), dim3(512), 0, stream>>>(qb, kbf, wvb, out);
}